// Round 3
// baseline (467.889 us; speedup 1.0000x reference)
//
#include <hip/hip_runtime.h>
#include <hip/hip_bf16.h>
#include <stdint.h>

#define AS1 __attribute__((address_space(1)))
#define AS3 __attribute__((address_space(3)))

typedef __attribute__((ext_vector_type(8))) short short8v;
typedef __attribute__((ext_vector_type(4))) float float4v;

#define NT 64
#define CCH 256
#define HH 56
#define WW 56
#define HWSZ 3136
#define HP 58
#define WP 58

// workspace layout (bytes)
#define OFF_XT   0ull
#define SZ_XT    110231552ull          // 64*58*58*256*2  (bf16 NHWC padded)
#define OFF_WPK  (OFF_XT + SZ_XT)
#define SZ_WPK   1179648ull            // 9*256*256*2
#define OFF_CS   (OFF_WPK + SZ_WPK)
#define SZ_CS    65536ull              // 64*256 f32 channel sums
#define OFF_XG2  (OFF_CS + SZ_CS)
#define SZ_XG2   8192ull               // 8*256 f32
#define OFF_WGT  (OFF_XG2 + SZ_XG2)
#define SZ_WGT   24576ull              // 8*256*3 f32
#define OFF_M    (OFF_WGT + SZ_WGT)
#define SZ_M     65536ull              // 8*256*8 f32
#define OFF_GATE (OFF_M + SZ_M)
#define SZ_GATE  65536ull              // 64*256 f32

__device__ __forceinline__ unsigned short f2bf(float f) {
    unsigned int u = __float_as_uint(f);
    unsigned int r = (u + 0x7fffu + ((u >> 16) & 1u)) >> 16;
    return (unsigned short)r;
}

__device__ __forceinline__ void gload16(const unsigned short* g, unsigned short* l) {
    __builtin_amdgcn_global_load_lds((const AS1 void*)g, (AS3 void*)l, 16, 0, 0);
}

// ---------------- K0: NCHW f32 -> NHWC-padded bf16 (with zero borders) ----
__global__ __launch_bounds__(256) void k0_transpose(const float* __restrict__ x,
                                                    unsigned short* __restrict__ xt) {
    int b = blockIdx.x;              // (nt, h, cb) : 64*56*4
    int cb = b & 3;
    int h  = (b >> 2) % 56;
    int nt = b / (4 * 56);
    int c0 = cb * 64;
    int tid = threadIdx.x;

    __shared__ float xs[64 * 57];    // padded stride 57 to dodge bank conflicts

    const float* src = x + ((size_t)nt * CCH + c0) * HWSZ + h * WW;
    for (int li = tid; li < 896; li += 256) {       // 64 rows * 14 float4
        int row = li / 14, f4 = li % 14;
        float4v v = *(const float4v*)(src + (size_t)row * HWSZ + f4 * 4);
        float* d = &xs[row * 57 + f4 * 4];
        d[0] = v.x; d[1] = v.y; d[2] = v.z; d[3] = v.w;
    }
    __syncthreads();

    unsigned short* dst = xt + (((size_t)nt * HP + (h + 1)) * WP) * CCH + c0;
    for (int job = tid; job < 464; job += 256) {    // 58 ww * 8 cgroups
        int ww = job >> 3, cg = job & 7;
        short8v v;
        if (ww == 0 || ww == 57) {
            v = (short8v){0,0,0,0,0,0,0,0};
        } else {
            #pragma unroll
            for (int jj = 0; jj < 8; ++jj)
                v[jj] = (short)f2bf(xs[(cg * 8 + jj) * 57 + (ww - 1)]);
        }
        *(short8v*)(dst + ww * CCH + cg * 8) = v;
    }
    if (h == 0) {   // zero rows hh=0 and hh=57
        unsigned short* d0  = xt + ((size_t)nt * HP + 0)  * WP * CCH + c0;
        unsigned short* d57 = xt + ((size_t)nt * HP + 57) * WP * CCH + c0;
        short8v z = (short8v){0,0,0,0,0,0,0,0};
        for (int job = tid; job < 464; job += 256) {
            int ww = job >> 3, cg = job & 7;
            *(short8v*)(d0  + ww * CCH + cg * 8) = z;
            *(short8v*)(d57 + ww * CCH + cg * 8) = z;
        }
    }
}

// ---------------- KW: pack conv weights -> [rs][k][c] bf16 ----------------
__global__ __launch_bounds__(256) void kw_pack(const float* __restrict__ nw,
                                               unsigned short* __restrict__ wpk) {
    int idx = blockIdx.x * 256 + threadIdx.x;       // 9*256*256 = 589824
    int rs = idx >> 16;
    int k  = (idx >> 8) & 255;
    int c  = idx & 255;
    wpk[idx] = f2bf(nw[(k * 256 + c) * 9 + rs]);
}

// ---------------- conv: implicit GEMM, 256x256x64 8-phase MFMA ------------
// A = wpk[rs][m][c] (weights), B = xt[pixel][c].  K = 36 tiles of 64 (9 rs x 4 co).
// LDS 128KB: A dbuf 2x16384 shorts, B dbuf 2x16384 shorts.
// st-swizzle: LDS slot (row, s) holds global k-chunk s ^ (row&7)  (16B chunks).

#define STG(nb, h, tA, tB) do { \
    gload16(wpk + (tA) + aoffs[h][0], &lds[(nb) * 16384 + ldst[h][0]]); \
    gload16(xt  + (tB) + boffs[h][0], &lds[32768 + (nb) * 16384 + ldst[h][0]]); \
    gload16(wpk + (tA) + aoffs[h][1], &lds[(nb) * 16384 + ldst[h][1]]); \
    gload16(xt  + (tB) + boffs[h][1], &lds[32768 + (nb) * 16384 + ldst[h][1]]); \
} while (0)

#define LDA8(row, kk) (*(const short8v*)&lds[abase + (row) * 64 + ((((kk) * 4 + hi) ^ xk) << 3)])
#define LDB8(row, kk) (*(const short8v*)&lds[bbase + (row) * 64 + ((((kk) * 4 + hi) ^ xk) << 3)])

// k-outer MFMA order: dependent accumulator reuse distance = 8 instructions
// (was 1 in R2 -> per-pair dep-latency bubbles with only 2 waves/SIMD).
#define QUAD(q) do { \
    const int _r0 = wm * 128 + (2 * (q)) * 16 + r16; \
    short8v _a00 = LDA8(_r0, 0); \
    short8v _a01 = LDA8(_r0, 1); \
    short8v _a10 = LDA8(_r0 + 16, 0); \
    short8v _a11 = LDA8(_r0 + 16, 1); \
    asm volatile("s_waitcnt lgkmcnt(0)" ::: "memory"); \
    __builtin_amdgcn_sched_barrier(0); \
    __builtin_amdgcn_s_setprio(1); \
    _Pragma("unroll") \
    for (int _j = 0; _j < 4; ++_j) \
        acc[2 * (q)][_j]     = __builtin_amdgcn_mfma_f32_16x16x32_bf16(_a00, bfrag[_j][0], acc[2 * (q)][_j], 0, 0, 0); \
    _Pragma("unroll") \
    for (int _j = 0; _j < 4; ++_j) \
        acc[2 * (q) + 1][_j] = __builtin_amdgcn_mfma_f32_16x16x32_bf16(_a10, bfrag[_j][0], acc[2 * (q) + 1][_j], 0, 0, 0); \
    _Pragma("unroll") \
    for (int _j = 0; _j < 4; ++_j) \
        acc[2 * (q)][_j]     = __builtin_amdgcn_mfma_f32_16x16x32_bf16(_a01, bfrag[_j][1], acc[2 * (q)][_j], 0, 0, 0); \
    _Pragma("unroll") \
    for (int _j = 0; _j < 4; ++_j) \
        acc[2 * (q) + 1][_j] = __builtin_amdgcn_mfma_f32_16x16x32_bf16(_a11, bfrag[_j][1], acc[2 * (q) + 1][_j], 0, 0, 0); \
    __builtin_amdgcn_s_setprio(0); \
} while (0)

#define BARSYNC do { \
    __builtin_amdgcn_s_barrier(); \
    __builtin_amdgcn_sched_barrier(0); \
} while (0)

__global__ __launch_bounds__(512, 2) void conv_mfma(const unsigned short* __restrict__ xt,
                                                    const unsigned short* __restrict__ wpk,
                                                    const float* __restrict__ net_b,
                                                    float* __restrict__ out,
                                                    float* __restrict__ chansum) {
    __shared__ unsigned short lds[65536];   // 128 KB: [A0|A1|B0|B1] x 16384 shorts

    const int tid  = threadIdx.x;
    const int lane = tid & 63;
    const int wid  = tid >> 6;         // 0..7
    const int wm   = wid >> 2;         // 0..1  (m half)
    const int wp   = wid & 3;          // 0..3  (p quarter)
    const int r16  = lane & 15;
    const int hi   = lane >> 4;        // 0..3
    const int xk   = r16 & 7;          // swizzle key for fragment reads

    // XCD-aware bijective swizzle: 784 = 8 * 98
    const int pblk = (blockIdx.x & 7) * 98 + (blockIdx.x >> 3);
    const int p0 = pblk * 256;

    // staging precompute: chunk ch = wid*128 + ld*64 + lane within a half-tile
    int aoffs[2][2]; long boffs[2][2]; int ldst[2][2];
    #pragma unroll
    for (int h = 0; h < 2; ++h) {
        #pragma unroll
        for (int ld = 0; ld < 2; ++ld) {
            int ch = wid * 128 + ld * 64 + lane;
            int rr = ch >> 3;                       // row within half (0..127)
            int kc = (ch & 7) ^ (rr & 7);           // pre-swizzled source chunk
            aoffs[h][ld] = (h * 128 + rr) * 256 + kc * 8;
            int p = p0 + h * 128 + rr;
            int nt = p / HWSZ, hw = p - nt * HWSZ;
            int hh = hw / WW,  w  = hw - hh * WW;
            boffs[h][ld] = ((long)(nt * HP + hh) * WP + w) * 256 + kc * 8;
            ldst[h][ld] = h * 8192 + (wid * 128 + ld * 64) * 8;
        }
    }

    float4v acc[8][4];
    #pragma unroll
    for (int i = 0; i < 8; ++i)
        #pragma unroll
        for (int j = 0; j < 4; ++j) acc[i][j] = (float4v){0.f, 0.f, 0.f, 0.f};

    // prologue: stage K-tile 0 into buf 0 (rs=0, co=0 -> offsets 0)
    STG(0, 0, 0, 0);
    STG(0, 1, 0, 0);

    for (int kt = 0; kt < 36; ++kt) {
        const int abase = (kt & 1) * 16384;
        const int bbase = 32768 + abase;
        const int nb = (kt & 1) ^ 1;
        const int ktn = kt + 1;
        const bool pf = ktn < 36;
        int tAn = 0, tBn = 0;
        if (pf) {
            const int rsn = ktn >> 2, con = (ktn & 3) * 64;
            tAn = rsn * 65536 + con;
            tBn = ((rsn / 3) * WP + (rsn - (rsn / 3) * 3)) * 256 + con;
        }

        // ---- phase 0: stage next A-half0/B-half0, counted wait, B frags + quad 0
        if (pf) {
            STG(nb, 0, tAn, tBn);
            asm volatile("s_waitcnt vmcnt(4)" ::: "memory");
        } else {
            asm volatile("s_waitcnt vmcnt(0)" ::: "memory");
        }
        BARSYNC;

        short8v bfrag[4][2];
        #pragma unroll
        for (int j = 0; j < 4; ++j) {
            const int br = wp * 64 + j * 16 + r16;
            bfrag[j][0] = LDB8(br, 0);
            bfrag[j][1] = LDB8(br, 1);
        }
        QUAD(0);
        BARSYNC;

        // ---- phase 1: stage next A-half1/B-half1, quad 1
        if (pf) STG(nb, 1, tAn, tBn);
        QUAD(1);
        BARSYNC;

        // ---- phase 2
        QUAD(2);
        BARSYNC;

        // ---- phase 3
        QUAD(3);
        BARSYNC;
    }

    // epilogue: bias + store + fused channel-sum
    const int pw = p0 + wp * 64;       // 64-aligned -> whole wave-chunk same image
    const int ntw = pw / HWSZ;
    const int hwb = pw - ntw * HWSZ;
    #pragma unroll
    for (int mi = 0; mi < 8; ++mi) {
        #pragma unroll
        for (int r = 0; r < 4; ++r) {
            const int m = wm * 128 + mi * 16 + hi * 4 + r;
            const float bias = net_b[m];
            float csum = 0.f;
            float* orow = out + ((size_t)ntw * CCH + m) * HWSZ + hwb;
            #pragma unroll
            for (int j = 0; j < 4; ++j) {
                float v = acc[mi][j][r] + bias;
                orow[j * 16 + r16] = v;
                csum += v;
            }
            csum += __shfl_xor(csum, 1);
            csum += __shfl_xor(csum, 2);
            csum += __shfl_xor(csum, 4);
            csum += __shfl_xor(csum, 8);
            if (r16 == 0) atomicAdd(&chansum[ntw * CCH + m], csum);
        }
    }
}

// ---------------- K2: x_g -> lam 1x1 conv -> xg2[n][c] --------------------
__global__ __launch_bounds__(256) void k2_xg(const float* __restrict__ chansum,
                                             const float* __restrict__ lam_w,
                                             const float* __restrict__ lam_b,
                                             float* __restrict__ xg2) {
    int n = blockIdx.x, c = threadIdx.x;
    __shared__ float xs[256];
    float s = 0.f;
    #pragma unroll
    for (int t = 0; t < 8; ++t) s += chansum[(n * 8 + t) * CCH + c];
    xs[c] = s * (1.0f / (3136.f * 8.f));
    __syncthreads();
    float d = lam_b[c];
    const float* row = lam_w + c * 256;
    for (int cc = 0; cc < 256; ++cc) d += row[cc] * xs[cc];
    xg2[n * 256 + c] = d;
}

// ---------------- K3: MLP+BN+softmax weights, m[n][c][t] ------------------
__global__ __launch_bounds__(256) void k3_wgt(const float* __restrict__ chansum,
                                              const float* __restrict__ xg2,
                                              const float* __restrict__ w1,
                                              const float* __restrict__ bg,
                                              const float* __restrict__ bb,
                                              const float* __restrict__ bm,
                                              const float* __restrict__ bv,
                                              const float* __restrict__ w2,
                                              float* __restrict__ wgt,
                                              float* __restrict__ mbuf) {
    int idx = blockIdx.x * 256 + threadIdx.x;    // n*256+c, 2048
    int n = idx >> 8, c = idx & 255;
    float xg = xg2[idx];
    float p[8];
    #pragma unroll
    for (int t = 0; t < 8; ++t)
        p[t] = chansum[(n * 8 + t) * CCH + c] * (1.0f / 3136.f) + xg;
    float hd[16];
    #pragma unroll
    for (int j = 0; j < 16; ++j) {
        float s = 0.f;
        #pragma unroll
        for (int t = 0; t < 8; ++t) s += p[t] * w1[j * 8 + t];
        s = (s - bm[j]) * (bg[j] * rsqrtf(bv[j] + 1e-5f)) + bb[j];
        hd[j] = fmaxf(s, 0.f);
    }
    float lg[3];
    #pragma unroll
    for (int k = 0; k < 3; ++k) {
        float s = 0.f;
        #pragma unroll
        for (int j = 0; j < 16; ++j) s += hd[j] * w2[k * 16 + j];
        lg[k] = s;
    }
    float mx = fmaxf(fmaxf(lg[0], lg[1]), lg[2]);
    float e0 = expf(lg[0] - mx), e1 = expf(lg[1] - mx), e2 = expf(lg[2] - mx);
    float inv = 1.f / (e0 + e1 + e2);
    float wk[3] = {e0 * inv, e1 * inv, e2 * inv};
    #pragma unroll
    for (int k = 0; k < 3; ++k) wgt[idx * 3 + k] = wk[k];
    #pragma unroll
    for (int t = 0; t < 8; ++t) {
        float s = 0.f;
        #pragma unroll
        for (int k = 0; k < 3; ++k) {
            int tt = t + k - 1;
            if (tt >= 0 && tt < 8) s += wk[k] * p[tt];
        }
        mbuf[idx * 8 + t] = s;
    }
}

// ---------------- K4: ME gate[nt][c] --------------------------------------
__global__ __launch_bounds__(256) void k4_gate(const float* __restrict__ mbuf,
                                               const float* __restrict__ me_w,
                                               float* __restrict__ gate) {
    int b = blockIdx.x;          // n*8+t
    int n = b >> 3, t = b & 7;
    int c = threadIdx.x;
    __shared__ float y[256];
    float yv = 0.f;
    if (t < 7) yv = mbuf[(n * 256 + c) * 8 + t + 1] - mbuf[(n * 256 + c) * 8 + t];
    y[c] = yv;
    __syncthreads();
    float yc = me_w[1] * yv;
    if (c > 0)   yc += me_w[0] * y[c - 1];
    if (c < 255) yc += me_w[2] * y[c + 1];
    gate[b * 256 + c] = 1.f / (1.f + expf(-yc));
}

// ---------------- K5: temporal mix + gate, in-place on d_out --------------
__global__ __launch_bounds__(256) void k5_final(float* __restrict__ out,
                                                const float* __restrict__ wgt,
                                                const float* __restrict__ xg2,
                                                const float* __restrict__ gate) {
    int tid = blockIdx.x * 256 + threadIdx.x;   // 2048 * 784
    int hw4 = tid % 784;
    int nc = tid / 784;
    int n = nc >> 8, c = nc & 255;
    float w0 = wgt[nc * 3 + 0], w1 = wgt[nc * 3 + 1], w2 = wgt[nc * 3 + 2];
    float xg = xg2[nc];
    const size_t tstride = (size_t)CCH * HWSZ;
    size_t base = ((size_t)(n * 8) * CCH + c) * HWSZ + hw4 * 4;

    float4v o[8];
    #pragma unroll
    for (int t = 0; t < 8; ++t) o[t] = *(const float4v*)(out + base + t * tstride);

    #pragma unroll
    for (int t = 0; t < 8; ++t) {
        float g = gate[(n * 8 + t) * CCH + c];
        float4v lam;
        #pragma unroll
        for (int q = 0; q < 4; ++q) {
            float v = w1 * (o[t][q] + xg);
            if (t > 0) v += w0 * (o[t - 1][q] + xg);
            if (t < 7) v += w2 * (o[t + 1][q] + xg);
            lam[q] = g * v;
        }
        *(float4v*)(out + base + t * tstride) = lam;
    }
}

extern "C" void kernel_launch(void* const* d_in, const int* in_sizes, int n_in,
                              void* d_out, int out_size, void* d_ws, size_t ws_size,
                              hipStream_t stream) {
    const float* x      = (const float*)d_in[0];
    const float* net_w  = (const float*)d_in[1];
    const float* net_b  = (const float*)d_in[2];
    const float* lam_w  = (const float*)d_in[3];
    const float* lam_b  = (const float*)d_in[4];
    const float* mlp_w1 = (const float*)d_in[5];
    const float* bn_g   = (const float*)d_in[6];
    const float* bn_b   = (const float*)d_in[7];
    const float* bn_m   = (const float*)d_in[8];
    const float* bn_v   = (const float*)d_in[9];
    const float* mlp_w2 = (const float*)d_in[10];
    const float* me_w   = (const float*)d_in[11];
    float* out = (float*)d_out;

    char* ws = (char*)d_ws;
    unsigned short* xt  = (unsigned short*)(ws + OFF_XT);
    unsigned short* wpk = (unsigned short*)(ws + OFF_WPK);
    float* chansum = (float*)(ws + OFF_CS);
    float* xg2     = (float*)(ws + OFF_XG2);
    float* wgt     = (float*)(ws + OFF_WGT);
    float* mbuf    = (float*)(ws + OFF_M);
    float* gate    = (float*)(ws + OFF_GATE);

    hipMemsetAsync(chansum, 0, SZ_CS, stream);
    kw_pack<<<2304, 256, 0, stream>>>(net_w, wpk);
    k0_transpose<<<64 * 56 * 4, 256, 0, stream>>>(x, xt);
    conv_mfma<<<784, 512, 0, stream>>>(xt, wpk, net_b, out, chansum);
    k2_xg<<<8, 256, 0, stream>>>(chansum, lam_w, lam_b, xg2);
    k3_wgt<<<8, 256, 0, stream>>>(chansum, xg2, mlp_w1, bn_g, bn_b, bn_m, bn_v, mlp_w2, wgt, mbuf);
    k4_gate<<<64, 256, 0, stream>>>(mbuf, me_w, gate);
    k5_final<<<6272, 256, 0, stream>>>(out, wgt, xg2, gate);
}

// Round 4
// 461.230 us; speedup vs baseline: 1.0144x; 1.0144x over previous
//
#include <hip/hip_runtime.h>
#include <hip/hip_bf16.h>
#include <stdint.h>

#define AS1 __attribute__((address_space(1)))
#define AS3 __attribute__((address_space(3)))

typedef __attribute__((ext_vector_type(8))) short short8v;
typedef __attribute__((ext_vector_type(4))) float float4v;

#define NT 64
#define CCH 256
#define HH 56
#define WW 56
#define HWSZ 3136
#define HP 58
#define WP 58

// workspace layout (bytes)
#define OFF_XT   0ull
#define SZ_XT    110231552ull          // 64*58*58*256*2  (bf16 NHWC padded)
#define OFF_WPK  (OFF_XT + SZ_XT)
#define SZ_WPK   1179648ull            // 9*256*256*2
#define OFF_CS   (OFF_WPK + SZ_WPK)
#define SZ_CS    65536ull              // 64*256 f32 channel sums
#define OFF_XG2  (OFF_CS + SZ_CS)
#define SZ_XG2   8192ull               // 8*256 f32
#define OFF_WGT  (OFF_XG2 + SZ_XG2)
#define SZ_WGT   24576ull              // 8*256*3 f32
#define OFF_M    (OFF_WGT + SZ_WGT)
#define SZ_M     65536ull              // 8*256*8 f32
#define OFF_GATE (OFF_M + SZ_M)
#define SZ_GATE  65536ull              // 64*256 f32

__device__ __forceinline__ unsigned short f2bf(float f) {
    unsigned int u = __float_as_uint(f);
    unsigned int r = (u + 0x7fffu + ((u >> 16) & 1u)) >> 16;
    return (unsigned short)r;
}

__device__ __forceinline__ void gload16(const unsigned short* g, unsigned short* l) {
    __builtin_amdgcn_global_load_lds((const AS1 void*)g, (AS3 void*)l, 16, 0, 0);
}

// ---------------- K0: NCHW f32 -> NHWC-padded bf16 (with zero borders) ----
__global__ __launch_bounds__(256) void k0_transpose(const float* __restrict__ x,
                                                    unsigned short* __restrict__ xt) {
    int b = blockIdx.x;              // (nt, h, cb) : 64*56*4
    int cb = b & 3;
    int h  = (b >> 2) % 56;
    int nt = b / (4 * 56);
    int c0 = cb * 64;
    int tid = threadIdx.x;

    __shared__ float xs[64 * 57];    // padded stride 57 to dodge bank conflicts

    const float* src = x + ((size_t)nt * CCH + c0) * HWSZ + h * WW;
    for (int li = tid; li < 896; li += 256) {       // 64 rows * 14 float4
        int row = li / 14, f4 = li % 14;
        float4v v = *(const float4v*)(src + (size_t)row * HWSZ + f4 * 4);
        float* d = &xs[row * 57 + f4 * 4];
        d[0] = v.x; d[1] = v.y; d[2] = v.z; d[3] = v.w;
    }
    __syncthreads();

    unsigned short* dst = xt + (((size_t)nt * HP + (h + 1)) * WP) * CCH + c0;
    for (int job = tid; job < 464; job += 256) {    // 58 ww * 8 cgroups
        int ww = job >> 3, cg = job & 7;
        short8v v;
        if (ww == 0 || ww == 57) {
            v = (short8v){0,0,0,0,0,0,0,0};
        } else {
            #pragma unroll
            for (int jj = 0; jj < 8; ++jj)
                v[jj] = (short)f2bf(xs[(cg * 8 + jj) * 57 + (ww - 1)]);
        }
        *(short8v*)(dst + ww * CCH + cg * 8) = v;
    }
    if (h == 0) {   // zero rows hh=0 and hh=57
        unsigned short* d0  = xt + ((size_t)nt * HP + 0)  * WP * CCH + c0;
        unsigned short* d57 = xt + ((size_t)nt * HP + 57) * WP * CCH + c0;
        short8v z = (short8v){0,0,0,0,0,0,0,0};
        for (int job = tid; job < 464; job += 256) {
            int ww = job >> 3, cg = job & 7;
            *(short8v*)(d0  + ww * CCH + cg * 8) = z;
            *(short8v*)(d57 + ww * CCH + cg * 8) = z;
        }
    }
}

// ---------------- KW: pack conv weights -> [rs][k][c] bf16 ----------------
__global__ __launch_bounds__(256) void kw_pack(const float* __restrict__ nw,
                                               unsigned short* __restrict__ wpk) {
    int idx = blockIdx.x * 256 + threadIdx.x;       // 9*256*256 = 589824
    int rs = idx >> 16;
    int k  = (idx >> 8) & 255;
    int c  = idx & 255;
    wpk[idx] = f2bf(nw[(k * 256 + c) * 9 + rs]);
}

// ---------------- conv: implicit GEMM, 256x256x64, 2-barrier-per-tile -----
// A = wpk[rs][m][c] (weights), B = xt[pixel][c].  K = 36 tiles of 64 (9 rs x 4 co).
// LDS 128KB: A dbuf 2x16384 shorts, B dbuf 2x16384 shorts.
// st-swizzle: LDS slot (row, s) holds global k-chunk s ^ (row&7)  (16B chunks).
// Barriers: 2 per K-tile. BAR#1 (after per-wave vmcnt drain) = RAW fence for
// the freshly staged buffer; BAR#2 (end of tile, after all lgkm-drained reads)
// = WAR fence allowing next iteration's STG into the other buffer.

#define STG(nb, h, tA, tB) do { \
    gload16(wpk + (tA) + aoffs[h][0], &lds[(nb) * 16384 + ldst[h][0]]); \
    gload16(xt  + (tB) + boffs[h][0], &lds[32768 + (nb) * 16384 + ldst[h][0]]); \
    gload16(wpk + (tA) + aoffs[h][1], &lds[(nb) * 16384 + ldst[h][1]]); \
    gload16(xt  + (tB) + boffs[h][1], &lds[32768 + (nb) * 16384 + ldst[h][1]]); \
} while (0)

#define LDA8(row, kk) (*(const short8v*)&lds[abase + (row) * 64 + ((((kk) * 4 + hi) ^ xk) << 3)])
#define LDB8(row, kk) (*(const short8v*)&lds[bbase + (row) * 64 + ((((kk) * 4 + hi) ^ xk) << 3)])

// 32-MFMA half-tile: m-rows [qq*64, qq*64+64) of this wave's 128-row range.
#define QUAD2(qq) do { \
    const int _r0 = wm * 128 + (qq) * 64 + r16; \
    short8v _a0k0 = LDA8(_r0, 0),      _a0k1 = LDA8(_r0, 1); \
    short8v _a1k0 = LDA8(_r0 + 16, 0), _a1k1 = LDA8(_r0 + 16, 1); \
    short8v _a2k0 = LDA8(_r0 + 32, 0), _a2k1 = LDA8(_r0 + 32, 1); \
    short8v _a3k0 = LDA8(_r0 + 48, 0), _a3k1 = LDA8(_r0 + 48, 1); \
    asm volatile("s_waitcnt lgkmcnt(0)" ::: "memory"); \
    __builtin_amdgcn_sched_barrier(0); \
    __builtin_amdgcn_s_setprio(1); \
    _Pragma("unroll") \
    for (int _j = 0; _j < 4; ++_j) { \
        acc[(qq) * 4 + 0][_j] = __builtin_amdgcn_mfma_f32_16x16x32_bf16(_a0k0, bfrag[_j][0], acc[(qq) * 4 + 0][_j], 0, 0, 0); \
        acc[(qq) * 4 + 1][_j] = __builtin_amdgcn_mfma_f32_16x16x32_bf16(_a1k0, bfrag[_j][0], acc[(qq) * 4 + 1][_j], 0, 0, 0); \
        acc[(qq) * 4 + 2][_j] = __builtin_amdgcn_mfma_f32_16x16x32_bf16(_a2k0, bfrag[_j][0], acc[(qq) * 4 + 2][_j], 0, 0, 0); \
        acc[(qq) * 4 + 3][_j] = __builtin_amdgcn_mfma_f32_16x16x32_bf16(_a3k0, bfrag[_j][0], acc[(qq) * 4 + 3][_j], 0, 0, 0); \
        acc[(qq) * 4 + 0][_j] = __builtin_amdgcn_mfma_f32_16x16x32_bf16(_a0k1, bfrag[_j][1], acc[(qq) * 4 + 0][_j], 0, 0, 0); \
        acc[(qq) * 4 + 1][_j] = __builtin_amdgcn_mfma_f32_16x16x32_bf16(_a1k1, bfrag[_j][1], acc[(qq) * 4 + 1][_j], 0, 0, 0); \
        acc[(qq) * 4 + 2][_j] = __builtin_amdgcn_mfma_f32_16x16x32_bf16(_a2k1, bfrag[_j][1], acc[(qq) * 4 + 2][_j], 0, 0, 0); \
        acc[(qq) * 4 + 3][_j] = __builtin_amdgcn_mfma_f32_16x16x32_bf16(_a3k1, bfrag[_j][1], acc[(qq) * 4 + 3][_j], 0, 0, 0); \
    } \
    __builtin_amdgcn_s_setprio(0); \
} while (0)

#define BARSYNC do { \
    __builtin_amdgcn_s_barrier(); \
    __builtin_amdgcn_sched_barrier(0); \
} while (0)

__global__ __launch_bounds__(512, 2) void conv_mfma(const unsigned short* __restrict__ xt,
                                                    const unsigned short* __restrict__ wpk,
                                                    const float* __restrict__ net_b,
                                                    float* __restrict__ out,
                                                    float* __restrict__ chansum) {
    __shared__ unsigned short lds[65536];   // 128 KB: [A0|A1|B0|B1] x 16384 shorts

    const int tid  = threadIdx.x;
    const int lane = tid & 63;
    const int wid  = tid >> 6;         // 0..7
    const int wm   = wid >> 2;         // 0..1  (m half)
    const int wp   = wid & 3;          // 0..3  (p quarter)
    const int r16  = lane & 15;
    const int hi   = lane >> 4;        // 0..3
    const int xk   = r16 & 7;          // swizzle key for fragment reads

    // XCD-aware bijective swizzle: 784 = 8 * 98
    const int pblk = (blockIdx.x & 7) * 98 + (blockIdx.x >> 3);
    const int p0 = pblk * 256;

    // staging precompute: chunk ch = wid*128 + ld*64 + lane within a half-tile
    int aoffs[2][2]; long boffs[2][2]; int ldst[2][2];
    #pragma unroll
    for (int h = 0; h < 2; ++h) {
        #pragma unroll
        for (int ld = 0; ld < 2; ++ld) {
            int ch = wid * 128 + ld * 64 + lane;
            int rr = ch >> 3;                       // row within half (0..127)
            int kc = (ch & 7) ^ (rr & 7);           // pre-swizzled source chunk
            aoffs[h][ld] = (h * 128 + rr) * 256 + kc * 8;
            int p = p0 + h * 128 + rr;
            int nt = p / HWSZ, hw = p - nt * HWSZ;
            int hh = hw / WW,  w  = hw - hh * WW;
            boffs[h][ld] = ((long)(nt * HP + hh) * WP + w) * 256 + kc * 8;
            ldst[h][ld] = h * 8192 + (wid * 128 + ld * 64) * 8;
        }
    }

    float4v acc[8][4];
    #pragma unroll
    for (int i = 0; i < 8; ++i)
        #pragma unroll
        for (int j = 0; j < 4; ++j) acc[i][j] = (float4v){0.f, 0.f, 0.f, 0.f};

    // prologue: stage K-tile 0 into buf 0 (rs=0, co=0 -> offsets 0)
    STG(0, 0, 0, 0);
    STG(0, 1, 0, 0);

    for (int kt = 0; kt < 36; ++kt) {
        const int abase = (kt & 1) * 16384;
        const int bbase = 32768 + abase;
        const int nb = (kt & 1) ^ 1;
        const int ktn = kt + 1;
        const bool pf = ktn < 36;
        int tAn = 0, tBn = 0;
        if (pf) {
            const int rsn = ktn >> 2, con = (ktn & 3) * 64;
            tAn = rsn * 65536 + con;
            tBn = ((rsn / 3) * WP + (rsn - (rsn / 3) * 3)) * 256 + con;
        }

        // ---- stage next half0, counted drain of THIS tile's 8 loads, RAW fence
        if (pf) {
            STG(nb, 0, tAn, tBn);
            asm volatile("s_waitcnt vmcnt(4)" ::: "memory");
        } else {
            asm volatile("s_waitcnt vmcnt(0)" ::: "memory");
        }
        BARSYNC;

        short8v bfrag[4][2];
        #pragma unroll
        for (int j = 0; j < 4; ++j) {
            const int br = wp * 64 + j * 16 + r16;
            bfrag[j][0] = LDB8(br, 0);
            bfrag[j][1] = LDB8(br, 1);
        }
        QUAD2(0);
        if (pf) STG(nb, 1, tAn, tBn);
        QUAD2(1);
        BARSYNC;                       // WAR fence: all reads of this buffer done
    }

    // epilogue: bias + store + fused channel-sum
    const int pw = p0 + wp * 64;       // 64-aligned -> whole wave-chunk same image
    const int ntw = pw / HWSZ;
    const int hwb = pw - ntw * HWSZ;
    #pragma unroll
    for (int mi = 0; mi < 8; ++mi) {
        #pragma unroll
        for (int r = 0; r < 4; ++r) {
            const int m = wm * 128 + mi * 16 + hi * 4 + r;
            const float bias = net_b[m];
            float csum = 0.f;
            float* orow = out + ((size_t)ntw * CCH + m) * HWSZ + hwb;
            #pragma unroll
            for (int j = 0; j < 4; ++j) {
                float v = acc[mi][j][r] + bias;
                orow[j * 16 + r16] = v;
                csum += v;
            }
            csum += __shfl_xor(csum, 1);
            csum += __shfl_xor(csum, 2);
            csum += __shfl_xor(csum, 4);
            csum += __shfl_xor(csum, 8);
            if (r16 == 0) atomicAdd(&chansum[ntw * CCH + m], csum);
        }
    }
}

// ---------------- K2: x_g -> lam 1x1 conv -> xg2[n][c] --------------------
__global__ __launch_bounds__(256) void k2_xg(const float* __restrict__ chansum,
                                             const float* __restrict__ lam_w,
                                             const float* __restrict__ lam_b,
                                             float* __restrict__ xg2) {
    int n = blockIdx.x, c = threadIdx.x;
    __shared__ float xs[256];
    float s = 0.f;
    #pragma unroll
    for (int t = 0; t < 8; ++t) s += chansum[(n * 8 + t) * CCH + c];
    xs[c] = s * (1.0f / (3136.f * 8.f));
    __syncthreads();
    float d = lam_b[c];
    const float* row = lam_w + c * 256;
    for (int cc = 0; cc < 256; ++cc) d += row[cc] * xs[cc];
    xg2[n * 256 + c] = d;
}

// ---------------- K3: MLP+BN+softmax weights, m[n][c][t] ------------------
__global__ __launch_bounds__(256) void k3_wgt(const float* __restrict__ chansum,
                                              const float* __restrict__ xg2,
                                              const float* __restrict__ w1,
                                              const float* __restrict__ bg,
                                              const float* __restrict__ bb,
                                              const float* __restrict__ bm,
                                              const float* __restrict__ bv,
                                              const float* __restrict__ w2,
                                              float* __restrict__ wgt,
                                              float* __restrict__ mbuf) {
    int idx = blockIdx.x * 256 + threadIdx.x;    // n*256+c, 2048
    int n = idx >> 8, c = idx & 255;
    float xg = xg2[idx];
    float p[8];
    #pragma unroll
    for (int t = 0; t < 8; ++t)
        p[t] = chansum[(n * 8 + t) * CCH + c] * (1.0f / 3136.f) + xg;
    float hd[16];
    #pragma unroll
    for (int j = 0; j < 16; ++j) {
        float s = 0.f;
        #pragma unroll
        for (int t = 0; t < 8; ++t) s += p[t] * w1[j * 8 + t];
        s = (s - bm[j]) * (bg[j] * rsqrtf(bv[j] + 1e-5f)) + bb[j];
        hd[j] = fmaxf(s, 0.f);
    }
    float lg[3];
    #pragma unroll
    for (int k = 0; k < 3; ++k) {
        float s = 0.f;
        #pragma unroll
        for (int j = 0; j < 16; ++j) s += hd[j] * w2[k * 16 + j];
        lg[k] = s;
    }
    float mx = fmaxf(fmaxf(lg[0], lg[1]), lg[2]);
    float e0 = expf(lg[0] - mx), e1 = expf(lg[1] - mx), e2 = expf(lg[2] - mx);
    float inv = 1.f / (e0 + e1 + e2);
    float wk[3] = {e0 * inv, e1 * inv, e2 * inv};
    #pragma unroll
    for (int k = 0; k < 3; ++k) wgt[idx * 3 + k] = wk[k];
    #pragma unroll
    for (int t = 0; t < 8; ++t) {
        float s = 0.f;
        #pragma unroll
        for (int k = 0; k < 3; ++k) {
            int tt = t + k - 1;
            if (tt >= 0 && tt < 8) s += wk[k] * p[tt];
        }
        mbuf[idx * 8 + t] = s;
    }
}

// ---------------- K4: ME gate[nt][c] --------------------------------------
__global__ __launch_bounds__(256) void k4_gate(const float* __restrict__ mbuf,
                                               const float* __restrict__ me_w,
                                               float* __restrict__ gate) {
    int b = blockIdx.x;          // n*8+t
    int n = b >> 3, t = b & 7;
    int c = threadIdx.x;
    __shared__ float y[256];
    float yv = 0.f;
    if (t < 7) yv = mbuf[(n * 256 + c) * 8 + t + 1] - mbuf[(n * 256 + c) * 8 + t];
    y[c] = yv;
    __syncthreads();
    float yc = me_w[1] * yv;
    if (c > 0)   yc += me_w[0] * y[c - 1];
    if (c < 255) yc += me_w[2] * y[c + 1];
    gate[b * 256 + c] = 1.f / (1.f + expf(-yc));
}

// ---------------- K5: temporal mix + gate, in-place on d_out --------------
__global__ __launch_bounds__(256) void k5_final(float* __restrict__ out,
                                                const float* __restrict__ wgt,
                                                const float* __restrict__ xg2,
                                                const float* __restrict__ gate) {
    int tid = blockIdx.x * 256 + threadIdx.x;   // 2048 * 784
    int hw4 = tid % 784;
    int nc = tid / 784;
    int n = nc >> 8, c = nc & 255;
    float w0 = wgt[nc * 3 + 0], w1 = wgt[nc * 3 + 1], w2 = wgt[nc * 3 + 2];
    float xg = xg2[nc];
    const size_t tstride = (size_t)CCH * HWSZ;
    size_t base = ((size_t)(n * 8) * CCH + c) * HWSZ + hw4 * 4;

    float4v o[8];
    #pragma unroll
    for (int t = 0; t < 8; ++t) o[t] = *(const float4v*)(out + base + t * tstride);

    #pragma unroll
    for (int t = 0; t < 8; ++t) {
        float g = gate[(n * 8 + t) * CCH + c];
        float4v lam;
        #pragma unroll
        for (int q = 0; q < 4; ++q) {
            float v = w1 * (o[t][q] + xg);
            if (t > 0) v += w0 * (o[t - 1][q] + xg);
            if (t < 7) v += w2 * (o[t + 1][q] + xg);
            lam[q] = g * v;
        }
        *(float4v*)(out + base + t * tstride) = lam;
    }
}

extern "C" void kernel_launch(void* const* d_in, const int* in_sizes, int n_in,
                              void* d_out, int out_size, void* d_ws, size_t ws_size,
                              hipStream_t stream) {
    const float* x      = (const float*)d_in[0];
    const float* net_w  = (const float*)d_in[1];
    const float* net_b  = (const float*)d_in[2];
    const float* lam_w  = (const float*)d_in[3];
    const float* lam_b  = (const float*)d_in[4];
    const float* mlp_w1 = (const float*)d_in[5];
    const float* bn_g   = (const float*)d_in[6];
    const float* bn_b   = (const float*)d_in[7];
    const float* bn_m   = (const float*)d_in[8];
    const float* bn_v   = (const float*)d_in[9];
    const float* mlp_w2 = (const float*)d_in[10];
    const float* me_w   = (const float*)d_in[11];
    float* out = (float*)d_out;

    char* ws = (char*)d_ws;
    unsigned short* xt  = (unsigned short*)(ws + OFF_XT);
    unsigned short* wpk = (unsigned short*)(ws + OFF_WPK);
    float* chansum = (float*)(ws + OFF_CS);
    float* xg2     = (float*)(ws + OFF_XG2);
    float* wgt     = (float*)(ws + OFF_WGT);
    float* mbuf    = (float*)(ws + OFF_M);
    float* gate    = (float*)(ws + OFF_GATE);

    hipMemsetAsync(chansum, 0, SZ_CS, stream);
    kw_pack<<<2304, 256, 0, stream>>>(net_w, wpk);
    k0_transpose<<<64 * 56 * 4, 256, 0, stream>>>(x, xt);
    conv_mfma<<<784, 512, 0, stream>>>(xt, wpk, net_b, out, chansum);
    k2_xg<<<8, 256, 0, stream>>>(chansum, lam_w, lam_b, xg2);
    k3_wgt<<<8, 256, 0, stream>>>(chansum, xg2, mlp_w1, bn_g, bn_b, bn_m, bn_v, mlp_w2, wgt, mbuf);
    k4_gate<<<64, 256, 0, stream>>>(mbuf, me_w, gate);
    k5_final<<<6272, 256, 0, stream>>>(out, wgt, xg2, gate);
}